// Round 27
// baseline (131.009 us; speedup 1.0000x reference)
//
#include <hip/hip_runtime.h>

typedef unsigned short u16;
typedef __attribute__((ext_vector_type(8))) short short8;
typedef __attribute__((ext_vector_type(4))) short s16x4;
typedef __attribute__((ext_vector_type(4))) float f32x4;
typedef __attribute__((ext_vector_type(16))) float f32x16;
typedef __attribute__((ext_vector_type(4))) unsigned u32x4;

#define S_LEN 2048
#define HID 2048
#define NQH 32
#define NKV 8
#define HD 64
#define QKVN 3072
#define SCLOG2 0.1803368801111204f  /* 0.125 * log2(e) */

__device__ __forceinline__ short f2b(float f){
  unsigned u = __builtin_bit_cast(unsigned, f);
  u += 0x7fffu + ((u >> 16) & 1u);
  return (short)(u >> 16);
}
__device__ __forceinline__ float b2f(u16 v){
  unsigned u = ((unsigned)v) << 16;
  return __builtin_bit_cast(float, u);
}
__device__ __forceinline__ void gll16(const void* g, void* l){
  __builtin_amdgcn_global_load_lds((const __attribute__((address_space(1))) void*)g,
                                   (__attribute__((address_space(3))) void*)l, 16, 0, 0);
}
__device__ __forceinline__ unsigned cvtpk(float a, float b){
  unsigned r;
  asm("v_cvt_pk_bf16_f32 %0, %1, %2" : "=v"(r) : "v"(a), "v"(b));
  return r;
}
__device__ __forceinline__ void pswap(unsigned &a, unsigned &b){
  asm volatile("v_permlane32_swap_b32 %0, %1" : "+v"(a), "+v"(b));
}
__device__ __forceinline__ float ex2(float x){
  float r; asm("v_exp_f32 %0, %1" : "=v"(r) : "v"(x)); return r;
}

// ------- fused fp32->bf16 convert (5 tensors) + RoPE table build --------------
__global__ __launch_bounds__(256) void cvt_all(const float* __restrict__ s0,
                                               const float* __restrict__ s1,
                                               const float* __restrict__ s2,
                                               const float* __restrict__ s3,
                                               const float* __restrict__ s4,
                                               u16* __restrict__ d0, u16* __restrict__ d1,
                                               u16* __restrict__ d2, u16* __restrict__ d3,
                                               u16* __restrict__ d4,
                                               const int* __restrict__ pos,
                                               const float* __restrict__ powers,
                                               float* __restrict__ cost,
                                               float* __restrict__ sint){
  int i = blockIdx.x * 256 + threadIdx.x;
  if (i >= 1835008) {
    int j = i - 1835008;                      // S_LEN*32
    int s = j >> 5, d = j & 31;
    float p = (float)pos[s];
    float w = powers[d];
    float sig = 1.0f / (1.0f + expf(-w));
    float inv = powf(10000.0f, -sig);
    float f = p * inv;
    cost[j] = cosf(f);
    sint[j] = sinf(f);
    return;
  }
  const float* s; u16* d; int off;
  if      (i <  524288){ s = s0; d = d0; off = i; }
  else if (i < 1048576){ s = s1; d = d1; off = i -  524288; }
  else if (i < 1179648){ s = s2; d = d2; off = i - 1048576; }
  else if (i < 1310720){ s = s3; d = d3; off = i - 1179648; }
  else                 { s = s4; d = d4; off = i - 1310720; }
  const float4* s4p = (const float4*)s;
  float4 a = s4p[off*2], b = s4p[off*2+1];
  short8 o = { f2b(a.x), f2b(a.y), f2b(a.z), f2b(a.w),
               f2b(b.x), f2b(b.y), f2b(b.z), f2b(b.w) };
  *(short8*)(d + (size_t)off*8) = o;
}

// ---------------- GEMM: C[M][Ntot] = A[M][K] * B[*][K]^T  (bf16 in) -----------
// 64 x (NCOLS*32) tile, NCOLS=2 -> 64x64 (32KB LDS, 5/CU capacity).
// QKV: grid (48,32)=1536 blocks, bf16 out (plain), V cols>=2560 transposed.
// Wo:  grid (32,32)=1024 blocks, f32 out.
// 2-phase double-buffer + both-sides XOR swizzle.
template<int MODE, int NCOLS>
__global__ __launch_bounds__(256) void gemm_bt(const u16* __restrict__ A,
                                               const u16* __restrict__ B0,
                                               const u16* __restrict__ B1,
                                               const u16* __restrict__ B2,
                                               int n1, int n2,
                                               void* __restrict__ Cout,
                                               u16* __restrict__ vtOut,
                                               int M, int Ntot, int K){
  __shared__ alignas(16) u16 sA[2][64*64];
  __shared__ alignas(16) u16 sB[2][NCOLS*32*64];
  const int tid = threadIdx.x, lane = tid & 63, wv = tid >> 6;
  const int wr = wv >> 1, wc = wv & 1;
  const int m0 = blockIdx.y * 64, n0 = blockIdx.x * (NCOLS*32);
  const int lr = lane & 15, lg = lane >> 4;

  const u16* B;
  if (n0 < n1)      B = B0 + (size_t)n0 * K;
  else if (n0 < n2) B = B1 + (size_t)(n0 - n1) * K;
  else              B = B2 + (size_t)(n0 - n2) * K;

  const int sRow = tid >> 3;
  const int sCol = ((tid & 7) ^ (sRow & 7)) * 8;   // pre-swizzled source column
  const u16* Arow = A + (size_t)(m0 + sRow)*K + sCol;
  const u16* Brow = B + (size_t)sRow*K + sCol;

  f32x4 acc[2][NCOLS] = {};
  const int NT = K >> 6;

  #pragma unroll
  for (int i = 0; i < 2; ++i)
    gll16(Arow + (size_t)i*32*K, (char*)&sA[0][0] + i*4096 + tid*16);
  #pragma unroll
  for (int i = 0; i < NCOLS; ++i)
    gll16(Brow + (size_t)i*32*K, (char*)&sB[0][0] + i*4096 + tid*16);
  __syncthreads();

  for (int t = 0; t < NT; ++t) {
    const int cur = t & 1;
    if (t + 1 < NT) {
      const int kn = (t + 1) << 6;
      #pragma unroll
      for (int i = 0; i < 2; ++i)
        gll16(Arow + (size_t)i*32*K + kn, (char*)&sA[cur^1][0] + i*4096 + tid*16);
      #pragma unroll
      for (int i = 0; i < NCOLS; ++i)
        gll16(Brow + (size_t)i*32*K + kn, (char*)&sB[cur^1][0] + i*4096 + tid*16);
    }
    const char* bA = (const char*)&sA[cur][0];
    const char* bB = (const char*)&sB[cur][0];
    #pragma unroll
    for (int kk = 0; kk < 64; kk += 32) {
      short8 af[2], bfr[NCOLS];
      #pragma unroll
      for (int m = 0; m < 2; ++m)
        af[m] = *(const short8*)(bA + (wr*32 + m*16 + lr)*128 + ((((kk>>3) + lg) ^ (lr & 7)) << 4));
      #pragma unroll
      for (int n = 0; n < NCOLS; ++n)
        bfr[n] = *(const short8*)(bB + (wc*(NCOLS*16) + n*16 + lr)*128 + ((((kk>>3) + lg) ^ (lr & 7)) << 4));
      #pragma unroll
      for (int m = 0; m < 2; ++m)
        #pragma unroll
        for (int n = 0; n < NCOLS; ++n)
          acc[m][n] = __builtin_amdgcn_mfma_f32_16x16x32_bf16(af[m], bfr[n], acc[m][n], 0, 0, 0);
    }
    asm volatile("s_waitcnt vmcnt(0)" ::: "memory");
    __builtin_amdgcn_s_barrier();
  }

  if (MODE == 0 && n0 >= 2560) {
    #pragma unroll
    for (int n = 0; n < NCOLS; ++n) {
      const int colv = n0 - 2560 + wc*(NCOLS*16) + n*16 + lr;
      #pragma unroll
      for (int m = 0; m < 2; ++m) {
        const int row = m0 + wr*32 + m*16 + lg*4;
        s16x4 o = { f2b(acc[m][n][0]), f2b(acc[m][n][1]),
                    f2b(acc[m][n][2]), f2b(acc[m][n][3]) };
        *(s16x4*)&vtOut[(size_t)colv*S_LEN + row] = o;
      }
    }
  } else if (MODE == 0) {
    // plain bf16 store; RoPE applied by the separate rope_apply pass
    #pragma unroll
    for (int m = 0; m < 2; ++m)
      #pragma unroll
      for (int n = 0; n < NCOLS; ++n)
        #pragma unroll
        for (int r = 0; r < 4; ++r) {
          int row = m0 + wr*32 + m*16 + lg*4 + r;
          int col = n0 + wc*(NCOLS*16) + n*16 + lr;
          ((u16*)Cout)[(size_t)row*Ntot + col] = (u16)f2b(acc[m][n][r]);
        }
  } else {
    #pragma unroll
    for (int m = 0; m < 2; ++m)
      #pragma unroll
      for (int n = 0; n < NCOLS; ++n)
        #pragma unroll
        for (int r = 0; r < 4; ++r) {
          int row = m0 + wr*32 + m*16 + lg*4 + r;
          int col = n0 + wc*(NCOLS*16) + n*16 + lr;
          ((float*)Cout)[(size_t)row*Ntot + col] = acc[m][n][r];
        }
  }
}

// ---------------- RoPE applied in-place on bf16 qkv (q,k regions) -------------
// grid S*40*4/256 = 1280 blocks. q heads also get the attn scale (SCLOG2).
__global__ __launch_bounds__(256) void rope_apply(u16* __restrict__ qkv,
                                                  const float* __restrict__ cost,
                                                  const float* __restrict__ sint){
  int i = blockIdx.x * 256 + threadIdx.x;   // S*40*4
  int g = i & 3;
  int hd = (i >> 2) % 40;
  int s = i / 160;
  const float qsc = (hd < NQH) ? SCLOG2 : 1.0f;
  int col = (hd < NQH) ? hd*HD : HID + (hd - NQH)*HD;
  u16* base = qkv + (size_t)s*QKVN + col + g*8;
  short8 lo = *(short8*)base;
  short8 hi = *(short8*)(base + 32);
  short8 olo, ohi;
  #pragma unroll
  for (int j = 0; j < 8; ++j) {
    float c  = cost[s*32 + g*8 + j];
    float sn = sint[s*32 + g*8 + j];
    float x1 = b2f((u16)lo[j]), x2 = b2f((u16)hi[j]);
    olo[j] = f2b((x1*c - x2*sn)*qsc);
    ohi[j] = f2b((x2*c + x1*sn)*qsc);
  }
  *(short8*)base = olo;
  *(short8*)(base + 32) = ohi;
}

// ---------------- flash attention: 32-row K tiles + 64-col V double-tiles -----
// (round-26 structure) grid (32 heads, 24 items) longest-first. chunks c<8
// unsplit (finalize); c>=8 split into 2 K-slices (bf16 partial O + f32 l ->
// combine). Rings: K 4x4KB; V 2x8KB double-tiles. LDS 32KB. Pair-ILP.
__global__ __launch_bounds__(256) void flash_attn(const u16* __restrict__ qkv,
                                                  const u16* __restrict__ vt,
                                                  u16* __restrict__ attn,
                                                  u16* __restrict__ pO,
                                                  float* __restrict__ pL){
  __shared__ alignas(16) u16 sK[4][32*64];
  __shared__ alignas(16) u16 sVT[2][64*64];
  static const int c_tab[24] = {7,15,15,14,14,6,13,13,12,12,5,11,11,
                                10,10,4,9,9,8,8,3,2,1,0};
  static const int s_tab[24] = {2,0,1,0,1,2,0,1,0,1,2,0,1,
                                0,1,2,0,1,0,1,2,2,2,2};
  const int tid = threadIdx.x, lane = tid & 63, w = tid >> 6;
  const int h = blockIdx.x, kvh = h >> 2;
  const int chunk = c_tab[blockIdx.y];
  const int sl = s_tab[blockIdx.y];
  int t0, ntb;                                // in 32-row tile units (even)
  if (sl == 2) { t0 = 0; ntb = 4*chunk + 4; }
  else         { t0 = sl*2*(chunk + 1); ntb = 2*(chunk + 1); }

  const int l5 = lane & 31, hi = lane >> 5;
  const int q0w = chunk*128 + w*32;
  const int qg = q0w + l5;

  const int kRow = lane >> 3;
  const u16* srcK = qkv + (size_t)(8*w + kRow)*QKVN + HID + kvh*HD
                    + ((lane & 7) ^ (kRow & 7))*8;
  const u16* srcV = vt + (size_t)(kvh*HD + 16*w + (lane >> 3))*S_LEN
                    + ((lane & 7) ^ (lane >> 3))*8;

  auto STAGE_K = [&](int t, int buf){
    gll16(srcK + (size_t)(t*32)*QKVN, (char*)&sK[buf][0] + w*1024);
  };
  auto STAGE_V = [&](int pair, int buf){
    char* dV = (char*)&sVT[buf][0] + w*2048;
    gll16(srcV + pair*64,                    dV);
    gll16(srcV + pair*64 + (size_t)8*S_LEN,  dV + 1024);
  };

  short8 qf[4];
  #pragma unroll
  for (int cc = 0; cc < 4; ++cc)
    qf[cc] = *(const short8*)&qkv[(size_t)(q0w + l5)*QKVN + h*HD + cc*16 + hi*8];

  f32x16 accO[2] = {};
  float l_part = 0.f;

  STAGE_K(t0, 0);
  STAGE_K(t0 + 1, 1);
  STAGE_V(t0 >> 1, (t0 >> 1) & 1);

  auto QK = [&](const char* bK)->f32x16{
    short8 kf[4];
    #pragma unroll
    for (int cc = 0; cc < 4; ++cc)
      kf[cc] = *(const short8*)(bK + l5*128 + (((cc*2 + hi) ^ (l5 & 7))*16));
    __builtin_amdgcn_s_setprio(1);
    f32x16 za = {}, zb = {};
    za = __builtin_amdgcn_mfma_f32_32x32x16_bf16(kf[0], qf[0], za, 0, 0, 0);
    zb = __builtin_amdgcn_mfma_f32_32x32x16_bf16(kf[1], qf[1], zb, 0, 0, 0);
    za = __builtin_amdgcn_mfma_f32_32x32x16_bf16(kf[2], qf[2], za, 0, 0, 0);
    zb = __builtin_amdgcn_mfma_f32_32x32x16_bf16(kf[3], qf[3], zb, 0, 0, 0);
    __builtin_amdgcn_s_setprio(0);
    return za + zb;
  };

  auto SMPV = [&](int kt, int p, const char* bV, f32x16& z){
    if (kt + 31 > q0w) {
      #pragma unroll
      for (int r = 0; r < 16; ++r) {
        const int k = kt + (r&3) + 8*(r>>2) + 4*hi;
        float e = ex2(z[r]);
        z[r] = (k > qg) ? 0.f : e;
      }
    } else {
      #pragma unroll
      for (int r = 0; r < 16; ++r) z[r] = ex2(z[r]);
    }
    float s0 = (z[0]+z[1]) + (z[2]+z[3]);
    float s1 = (z[4]+z[5]) + (z[6]+z[7]);
    float s2 = (z[8]+z[9]) + (z[10]+z[11]);
    float s3 = (z[12]+z[13]) + (z[14]+z[15]);
    l_part += (s0+s1) + (s2+s3);

    short8 pa[2];
    {
      unsigned a0 = cvtpk(z[0],  z[1]);
      unsigned c0 = cvtpk(z[2],  z[3]);
      unsigned b0 = cvtpk(z[4],  z[5]);
      unsigned d0 = cvtpk(z[6],  z[7]);
      pswap(a0, b0); pswap(c0, d0);
      u32x4 w0 = {a0, c0, b0, d0};
      pa[0] = __builtin_bit_cast(short8, w0);
      unsigned a1 = cvtpk(z[8],  z[9]);
      unsigned c1 = cvtpk(z[10], z[11]);
      unsigned b1 = cvtpk(z[12], z[13]);
      unsigned d1 = cvtpk(z[14], z[15]);
      pswap(a1, b1); pswap(c1, d1);
      u32x4 w1 = {a1, c1, b1, d1};
      pa[1] = __builtin_bit_cast(short8, w1);
    }
    __builtin_amdgcn_s_setprio(1);
    #pragma unroll
    for (int s4 = 0; s4 < 2; ++s4)
      #pragma unroll
      for (int db = 0; db < 2; ++db) {
        short8 vf = *(const short8*)(bV + (db*32 + l5)*128 + (((p*4 + s4*2 + hi) ^ (l5 & 7))*16));
        accO[db] = __builtin_amdgcn_mfma_f32_32x32x16_bf16(vf, pa[s4], accO[db], 0, 0, 0);
      }
    __builtin_amdgcn_s_setprio(0);
  };

  for (int lt = 0; lt < ntb; lt += 2) {
    const int gp = (t0 + lt) >> 1;             // global V double-tile index
    asm volatile("s_waitcnt vmcnt(0)" ::: "memory");
    __builtin_amdgcn_s_barrier();
    if (lt + 2 < ntb) {
      STAGE_K(t0 + lt + 2, (lt + 2) & 3);
      STAGE_K(t0 + lt + 3, (lt + 3) & 3);
      STAGE_V(gp + 1, (gp + 1) & 1);
    }

    const int ktA = (t0 + lt)*32, ktB = ktA + 32;
    const bool doA = (ktA <= q0w + 31);
    const bool doB = (ktB <= q0w + 31);
    const char* bKA = (const char*)&sK[lt & 3][0];
    const char* bKB = (const char*)&sK[(lt + 1) & 3][0];
    const char* bV  = (const char*)&sVT[gp & 1][0];

    f32x16 stA, stB;
    if (doA) stA = QK(bKA);
    if (doB) stB = QK(bKB);
    if (doA) SMPV(ktA, 0, bV, stA);
    if (doB) SMPV(ktB, 1, bV, stB);
  }

  const float l_run = l_part + __shfl_xor(l_part, 32);
  if (sl == 2) {
    const float invl = 1.0f / l_run;
    #pragma unroll
    for (int db = 0; db < 2; ++db)
      #pragma unroll
      for (int g2 = 0; g2 < 4; ++g2) {
        s16x4 o = { f2b(accO[db][g2*4+0]*invl), f2b(accO[db][g2*4+1]*invl),
                    f2b(accO[db][g2*4+2]*invl), f2b(accO[db][g2*4+3]*invl) };
        *(s16x4*)&attn[(size_t)(q0w + l5)*HID + h*HD + db*32 + g2*8 + hi*4] = o;
      }
  } else {
    const int slot = (h*8 + (chunk - 8))*2 + sl;
    const int row = w*32 + l5;
    u16* po = pO + (size_t)slot*128*64 + (size_t)row*64;
    #pragma unroll
    for (int db = 0; db < 2; ++db)
      #pragma unroll
      for (int g2 = 0; g2 < 4; ++g2) {
        s16x4 o = { f2b(accO[db][g2*4+0]), f2b(accO[db][g2*4+1]),
                    f2b(accO[db][g2*4+2]), f2b(accO[db][g2*4+3]) };
        *(s16x4*)&po[db*32 + g2*8 + hi*4] = o;
      }
    if (lane < 32)
      pL[(size_t)slot*128 + row] = l_run;
  }
}

// ---------------- combine: sum the 2 K-slice partials of chunks 8..15 ---------
__global__ __launch_bounds__(256) void combine(const u16* __restrict__ pO,
                                               const float* __restrict__ pL,
                                               u16* __restrict__ attn){
  int i = blockIdx.x * 256 + threadIdx.x;
  int d8 = i & 7;
  int row = (i >> 3) & 127;
  int cc = (i >> 10) & 7;
  int h = i >> 13;
  int slot0 = (h*8 + cc)*2;
  float l = pL[(size_t)slot0*128 + row] + pL[(size_t)(slot0+1)*128 + row];
  short8 v0 = *(const short8*)&pO[((size_t)slot0*128 + row)*64 + d8*8];
  short8 v1 = *(const short8*)&pO[((size_t)(slot0+1)*128 + row)*64 + d8*8];
  const float inv = 1.0f / l;
  short8 o;
  #pragma unroll
  for (int j = 0; j < 8; ++j)
    o[j] = f2b((b2f((u16)v0[j]) + b2f((u16)v1[j])) * inv);
  const int q = (8 + cc)*128 + row;
  *(short8*)&attn[(size_t)q*HID + h*HD + d8*8] = o;
}

// ---------------- launch ----------------
extern "C" void kernel_launch(void* const* d_in, const int* in_sizes, int n_in,
                              void* d_out, int out_size, void* d_ws, size_t ws_size,
                              hipStream_t stream){
  const float* hs     = (const float*)d_in[0];
  const int*   pos    = (const int*)d_in[1];
  const float* powers = (const float*)d_in[2];
  const float* Wq     = (const float*)d_in[3];
  const float* Wk     = (const float*)d_in[4];
  const float* Wv     = (const float*)d_in[5];
  const float* Wo     = (const float*)d_in[6];
  float* out = (float*)d_out;

  char* ws = (char*)d_ws;
  auto take = [&](size_t bytes){ void* p = ws; ws += (bytes + 255) & ~(size_t)255; return p; };
  u16* hs_b  = (u16*)take((size_t)S_LEN*HID*2);
  u16* wq_b  = (u16*)take((size_t)HID*HID*2);
  u16* wk_b  = (u16*)take((size_t)NKV*HD*HID*2);
  u16* wv_b  = (u16*)take((size_t)NKV*HD*HID*2);
  u16* wo_b  = (u16*)take((size_t)HID*HID*2);
  u16* qkv   = (u16*)take((size_t)S_LEN*QKVN*2);
  u16* vt    = (u16*)take((size_t)NKV*HD*S_LEN*2);
  u16* attnb = (u16*)take((size_t)S_LEN*HID*2);
  float* cost = (float*)take((size_t)S_LEN*32*4);
  float* sint = (float*)take((size_t)S_LEN*32*4);
  u16* pO    = (u16*)take((size_t)NQH*8*2*128*64*2);     // 8.4 MB bf16 partial O
  float* pL  = (float*)take((size_t)NQH*8*2*128*4);      // 256 KB partial l

  cvt_all<<<7424, 256, 0, stream>>>(hs, Wq, Wk, Wv, Wo,
                                    hs_b, wq_b, wk_b, wv_b, wo_b,
                                    pos, powers, cost, sint);

  // fused QKV projection (plain bf16 out; V written transposed into vt)
  gemm_bt<0, 2><<<dim3(QKVN/64, S_LEN/64), 256, 0, stream>>>(
      hs_b, wq_b, wk_b, wv_b, HID, HID + NKV*HD, qkv, vt,
      S_LEN, QKVN, HID);

  rope_apply<<<S_LEN*40*4/256, 256, 0, stream>>>(qkv, cost, sint);

  flash_attn<<<dim3(NQH, 24), 256, 0, stream>>>(qkv, vt, attnb, pO, pL);
  combine<<<1024, 256, 0, stream>>>(pO, pL, attnb);

  gemm_bt<1, 2><<<dim3(HID/64, S_LEN/64), 256, 0, stream>>>(
      attnb, wo_b, wo_b, wo_b, 1<<28, 1<<29, out, nullptr,
      S_LEN, HID, HID);
}

// Round 28
// 111.904 us; speedup vs baseline: 1.1707x; 1.1707x over previous
//
#include <hip/hip_runtime.h>

typedef unsigned short u16;
typedef __attribute__((ext_vector_type(8))) short short8;
typedef __attribute__((ext_vector_type(4))) short s16x4;
typedef __attribute__((ext_vector_type(4))) float f32x4;
typedef __attribute__((ext_vector_type(16))) float f32x16;
typedef __attribute__((ext_vector_type(4))) unsigned u32x4;

#define S_LEN 2048
#define HID 2048
#define NQH 32
#define NKV 8
#define HD 64
#define QKVN 3072
#define SCLOG2 0.1803368801111204f  /* 0.125 * log2(e) */

__device__ __forceinline__ short f2b(float f){
  unsigned u = __builtin_bit_cast(unsigned, f);
  u += 0x7fffu + ((u >> 16) & 1u);
  return (short)(u >> 16);
}
__device__ __forceinline__ float b2f(u16 v){
  unsigned u = ((unsigned)v) << 16;
  return __builtin_bit_cast(float, u);
}
__device__ __forceinline__ void gll16(const void* g, void* l){
  __builtin_amdgcn_global_load_lds((const __attribute__((address_space(1))) void*)g,
                                   (__attribute__((address_space(3))) void*)l, 16, 0, 0);
}
__device__ __forceinline__ unsigned cvtpk(float a, float b){
  unsigned r;
  asm("v_cvt_pk_bf16_f32 %0, %1, %2" : "=v"(r) : "v"(a), "v"(b));
  return r;
}
__device__ __forceinline__ void pswap(unsigned &a, unsigned &b){
  asm volatile("v_permlane32_swap_b32 %0, %1" : "+v"(a), "+v"(b));
}
__device__ __forceinline__ float ex2(float x){
  float r; asm("v_exp_f32 %0, %1" : "=v"(r) : "v"(x)); return r;
}

// ------- fused fp32->bf16 convert (5 tensors) + RoPE table build --------------
__global__ __launch_bounds__(256) void cvt_all(const float* __restrict__ s0,
                                               const float* __restrict__ s1,
                                               const float* __restrict__ s2,
                                               const float* __restrict__ s3,
                                               const float* __restrict__ s4,
                                               u16* __restrict__ d0, u16* __restrict__ d1,
                                               u16* __restrict__ d2, u16* __restrict__ d3,
                                               u16* __restrict__ d4,
                                               const int* __restrict__ pos,
                                               const float* __restrict__ powers,
                                               float* __restrict__ cost,
                                               float* __restrict__ sint){
  int i = blockIdx.x * 256 + threadIdx.x;
  if (i >= 1835008) {
    int j = i - 1835008;                      // S_LEN*32
    int s = j >> 5, d = j & 31;
    float p = (float)pos[s];
    float w = powers[d];
    float sig = 1.0f / (1.0f + expf(-w));
    float inv = powf(10000.0f, -sig);
    float f = p * inv;
    cost[j] = cosf(f);
    sint[j] = sinf(f);
    return;
  }
  const float* s; u16* d; int off;
  if      (i <  524288){ s = s0; d = d0; off = i; }
  else if (i < 1048576){ s = s1; d = d1; off = i -  524288; }
  else if (i < 1179648){ s = s2; d = d2; off = i - 1048576; }
  else if (i < 1310720){ s = s3; d = d3; off = i - 1179648; }
  else                 { s = s4; d = d4; off = i - 1310720; }
  const float4* s4p = (const float4*)s;
  float4 a = s4p[off*2], b = s4p[off*2+1];
  short8 o = { f2b(a.x), f2b(a.y), f2b(a.z), f2b(a.w),
               f2b(b.x), f2b(b.y), f2b(b.z), f2b(b.w) };
  *(short8*)(d + (size_t)off*8) = o;
}

// ---------------- GEMM: C[M][Ntot] = A[M][K] * B[*][K]^T  (bf16 in) -----------
// 64 x (NCOLS*32) tile. QKV: NCOLS=4 -> 768 blocks (3/CU, 48KB). Wo: NCOLS=2
// -> 1024 blocks (4/CU, 32KB). 2-phase double-buffer + both-sides XOR swizzle.
// XCD-aware bijective block swizzle (grids are multiples of 8).
// MODE 0 (QKV): bf16 out, RoPE (+attn-scale on q) cols<2560, V transposed.
// MODE 1 (Wo): f32 out.
template<int MODE, int NCOLS>
__global__ __launch_bounds__(256) void gemm_bt(const u16* __restrict__ A,
                                               const u16* __restrict__ B0,
                                               const u16* __restrict__ B1,
                                               const u16* __restrict__ B2,
                                               int n1, int n2,
                                               void* __restrict__ Cout,
                                               u16* __restrict__ vtOut,
                                               int M, int Ntot, int K,
                                               const float* __restrict__ cost,
                                               const float* __restrict__ sint){
  __shared__ alignas(16) u16 sA[2][64*64];
  __shared__ alignas(16) u16 sB[2][NCOLS*32*64];
  const int tid = threadIdx.x, lane = tid & 63, wv = tid >> 6;
  const int wr = wv >> 1, wc = wv & 1;
  // XCD-aware bijective swizzle: blocks co-resident on one XCD get a
  // contiguous tile range (shared A-panels stay in that XCD's L2).
  const int nwg = gridDim.x * gridDim.y;
  const int lin = blockIdx.y * gridDim.x + blockIdx.x;
  const int swz = (lin & 7) * (nwg >> 3) + (lin >> 3);
  const int m0 = (swz / gridDim.x) * 64;
  const int n0 = (swz % gridDim.x) * (NCOLS*32);
  const int lr = lane & 15, lg = lane >> 4;

  const u16* B;
  if (n0 < n1)      B = B0 + (size_t)n0 * K;
  else if (n0 < n2) B = B1 + (size_t)(n0 - n1) * K;
  else              B = B2 + (size_t)(n0 - n2) * K;

  const int sRow = tid >> 3;
  const int sCol = ((tid & 7) ^ (sRow & 7)) * 8;   // pre-swizzled source column
  const u16* Arow = A + (size_t)(m0 + sRow)*K + sCol;
  const u16* Brow = B + (size_t)sRow*K + sCol;

  f32x4 acc[2][NCOLS] = {};
  const int NT = K >> 6;

  #pragma unroll
  for (int i = 0; i < 2; ++i)
    gll16(Arow + (size_t)i*32*K, (char*)&sA[0][0] + i*4096 + tid*16);
  #pragma unroll
  for (int i = 0; i < NCOLS; ++i)
    gll16(Brow + (size_t)i*32*K, (char*)&sB[0][0] + i*4096 + tid*16);
  __syncthreads();

  for (int t = 0; t < NT; ++t) {
    const int cur = t & 1;
    if (t + 1 < NT) {
      const int kn = (t + 1) << 6;
      #pragma unroll
      for (int i = 0; i < 2; ++i)
        gll16(Arow + (size_t)i*32*K + kn, (char*)&sA[cur^1][0] + i*4096 + tid*16);
      #pragma unroll
      for (int i = 0; i < NCOLS; ++i)
        gll16(Brow + (size_t)i*32*K + kn, (char*)&sB[cur^1][0] + i*4096 + tid*16);
    }
    const char* bA = (const char*)&sA[cur][0];
    const char* bB = (const char*)&sB[cur][0];
    #pragma unroll
    for (int kk = 0; kk < 64; kk += 32) {
      short8 af[2], bfr[NCOLS];
      #pragma unroll
      for (int m = 0; m < 2; ++m)
        af[m] = *(const short8*)(bA + (wr*32 + m*16 + lr)*128 + ((((kk>>3) + lg) ^ (lr & 7)) << 4));
      #pragma unroll
      for (int n = 0; n < NCOLS; ++n)
        bfr[n] = *(const short8*)(bB + (wc*(NCOLS*16) + n*16 + lr)*128 + ((((kk>>3) + lg) ^ (lr & 7)) << 4));
      #pragma unroll
      for (int m = 0; m < 2; ++m)
        #pragma unroll
        for (int n = 0; n < NCOLS; ++n)
          acc[m][n] = __builtin_amdgcn_mfma_f32_16x16x32_bf16(af[m], bfr[n], acc[m][n], 0, 0, 0);
    }
    asm volatile("s_waitcnt vmcnt(0)" ::: "memory");
    __builtin_amdgcn_s_barrier();
  }

  if (MODE == 0 && n0 >= 2560) {
    #pragma unroll
    for (int n = 0; n < NCOLS; ++n) {
      const int colv = n0 - 2560 + wc*(NCOLS*16) + n*16 + lr;
      #pragma unroll
      for (int m = 0; m < 2; ++m) {
        const int row = m0 + wr*32 + m*16 + lg*4;
        s16x4 o = { f2b(acc[m][n][0]), f2b(acc[m][n][1]),
                    f2b(acc[m][n][2]), f2b(acc[m][n][3]) };
        *(s16x4*)&vtOut[(size_t)colv*S_LEN + row] = o;
      }
    }
  } else if (MODE == 0) {
    const float qsc = (n0 < n1) ? SCLOG2 : 1.0f;
    #pragma unroll
    for (int m = 0; m < 2; ++m)
      #pragma unroll
      for (int r = 0; r < 4; ++r) {
        int row = m0 + wr*32 + m*16 + lg*4 + r;
        float c0 = cost[row*32 + lr],      s0 = sint[row*32 + lr];
        float c1 = cost[row*32 + 16 + lr], s1 = sint[row*32 + 16 + lr];
        float x0 = acc[m][0][r], x1 = acc[m][1][r];
        float x2 = acc[m][2][r], x3 = acc[m][3][r];
        float o0 = (x0*c0 - x2*s0)*qsc, o2 = (x2*c0 + x0*s0)*qsc;
        float o1 = (x1*c1 - x3*s1)*qsc, o3 = (x3*c1 + x1*s1)*qsc;
        u16* cp = (u16*)Cout + (size_t)row*Ntot + n0 + wc*64 + lr;
        cp[0]  = (u16)f2b(o0);
        cp[16] = (u16)f2b(o1);
        cp[32] = (u16)f2b(o2);
        cp[48] = (u16)f2b(o3);
      }
  } else {
    #pragma unroll
    for (int m = 0; m < 2; ++m)
      #pragma unroll
      for (int n = 0; n < NCOLS; ++n)
        #pragma unroll
        for (int r = 0; r < 4; ++r) {
          int row = m0 + wr*32 + m*16 + lg*4 + r;
          int col = n0 + wc*(NCOLS*16) + n*16 + lr;
          ((float*)Cout)[(size_t)row*Ntot + col] = acc[m][n][r];
        }
  }
}

// ---------------- flash attention: 32-row K tiles + 64-col V double-tiles -----
// (round-26 structure) grid (32 heads, 24 items) longest-first. chunks c<8
// unsplit (finalize); c>=8 split into 2 K-slices (bf16 partial O + f32 l ->
// combine). Rings: K 4x4KB; V 2x8KB double-tiles. LDS 32KB. Pair-ILP.
__global__ __launch_bounds__(256) void flash_attn(const u16* __restrict__ qkv,
                                                  const u16* __restrict__ vt,
                                                  u16* __restrict__ attn,
                                                  u16* __restrict__ pO,
                                                  float* __restrict__ pL){
  __shared__ alignas(16) u16 sK[4][32*64];
  __shared__ alignas(16) u16 sVT[2][64*64];
  static const int c_tab[24] = {7,15,15,14,14,6,13,13,12,12,5,11,11,
                                10,10,4,9,9,8,8,3,2,1,0};
  static const int s_tab[24] = {2,0,1,0,1,2,0,1,0,1,2,0,1,
                                0,1,2,0,1,0,1,2,2,2,2};
  const int tid = threadIdx.x, lane = tid & 63, w = tid >> 6;
  const int h = blockIdx.x, kvh = h >> 2;
  const int chunk = c_tab[blockIdx.y];
  const int sl = s_tab[blockIdx.y];
  int t0, ntb;                                // in 32-row tile units (even)
  if (sl == 2) { t0 = 0; ntb = 4*chunk + 4; }
  else         { t0 = sl*2*(chunk + 1); ntb = 2*(chunk + 1); }

  const int l5 = lane & 31, hi = lane >> 5;
  const int q0w = chunk*128 + w*32;
  const int qg = q0w + l5;

  const int kRow = lane >> 3;
  const u16* srcK = qkv + (size_t)(8*w + kRow)*QKVN + HID + kvh*HD
                    + ((lane & 7) ^ (kRow & 7))*8;
  const u16* srcV = vt + (size_t)(kvh*HD + 16*w + (lane >> 3))*S_LEN
                    + ((lane & 7) ^ (lane >> 3))*8;

  auto STAGE_K = [&](int t, int buf){
    gll16(srcK + (size_t)(t*32)*QKVN, (char*)&sK[buf][0] + w*1024);
  };
  auto STAGE_V = [&](int pair, int buf){
    char* dV = (char*)&sVT[buf][0] + w*2048;
    gll16(srcV + pair*64,                    dV);
    gll16(srcV + pair*64 + (size_t)8*S_LEN,  dV + 1024);
  };

  short8 qf[4];
  #pragma unroll
  for (int cc = 0; cc < 4; ++cc)
    qf[cc] = *(const short8*)&qkv[(size_t)(q0w + l5)*QKVN + h*HD + cc*16 + hi*8];

  f32x16 accO[2] = {};
  float l_part = 0.f;

  STAGE_K(t0, 0);
  STAGE_K(t0 + 1, 1);
  STAGE_V(t0 >> 1, (t0 >> 1) & 1);

  auto QK = [&](const char* bK)->f32x16{
    short8 kf[4];
    #pragma unroll
    for (int cc = 0; cc < 4; ++cc)
      kf[cc] = *(const short8*)(bK + l5*128 + (((cc*2 + hi) ^ (l5 & 7))*16));
    __builtin_amdgcn_s_setprio(1);
    f32x16 za = {}, zb = {};
    za = __builtin_amdgcn_mfma_f32_32x32x16_bf16(kf[0], qf[0], za, 0, 0, 0);
    zb = __builtin_amdgcn_mfma_f32_32x32x16_bf16(kf[1], qf[1], zb, 0, 0, 0);
    za = __builtin_amdgcn_mfma_f32_32x32x16_bf16(kf[2], qf[2], za, 0, 0, 0);
    zb = __builtin_amdgcn_mfma_f32_32x32x16_bf16(kf[3], qf[3], zb, 0, 0, 0);
    __builtin_amdgcn_s_setprio(0);
    return za + zb;
  };

  auto SMPV = [&](int kt, int p, const char* bV, f32x16& z){
    if (kt + 31 > q0w) {
      #pragma unroll
      for (int r = 0; r < 16; ++r) {
        const int k = kt + (r&3) + 8*(r>>2) + 4*hi;
        float e = ex2(z[r]);
        z[r] = (k > qg) ? 0.f : e;
      }
    } else {
      #pragma unroll
      for (int r = 0; r < 16; ++r) z[r] = ex2(z[r]);
    }
    float s0 = (z[0]+z[1]) + (z[2]+z[3]);
    float s1 = (z[4]+z[5]) + (z[6]+z[7]);
    float s2 = (z[8]+z[9]) + (z[10]+z[11]);
    float s3 = (z[12]+z[13]) + (z[14]+z[15]);
    l_part += (s0+s1) + (s2+s3);

    short8 pa[2];
    {
      unsigned a0 = cvtpk(z[0],  z[1]);
      unsigned c0 = cvtpk(z[2],  z[3]);
      unsigned b0 = cvtpk(z[4],  z[5]);
      unsigned d0 = cvtpk(z[6],  z[7]);
      pswap(a0, b0); pswap(c0, d0);
      u32x4 w0 = {a0, c0, b0, d0};
      pa[0] = __builtin_bit_cast(short8, w0);
      unsigned a1 = cvtpk(z[8],  z[9]);
      unsigned c1 = cvtpk(z[10], z[11]);
      unsigned b1 = cvtpk(z[12], z[13]);
      unsigned d1 = cvtpk(z[14], z[15]);
      pswap(a1, b1); pswap(c1, d1);
      u32x4 w1 = {a1, c1, b1, d1};
      pa[1] = __builtin_bit_cast(short8, w1);
    }
    __builtin_amdgcn_s_setprio(1);
    #pragma unroll
    for (int s4 = 0; s4 < 2; ++s4)
      #pragma unroll
      for (int db = 0; db < 2; ++db) {
        short8 vf = *(const short8*)(bV + (db*32 + l5)*128 + (((p*4 + s4*2 + hi) ^ (l5 & 7))*16));
        accO[db] = __builtin_amdgcn_mfma_f32_32x32x16_bf16(vf, pa[s4], accO[db], 0, 0, 0);
      }
    __builtin_amdgcn_s_setprio(0);
  };

  for (int lt = 0; lt < ntb; lt += 2) {
    const int gp = (t0 + lt) >> 1;             // global V double-tile index
    asm volatile("s_waitcnt vmcnt(0)" ::: "memory");
    __builtin_amdgcn_s_barrier();
    if (lt + 2 < ntb) {
      STAGE_K(t0 + lt + 2, (lt + 2) & 3);
      STAGE_K(t0 + lt + 3, (lt + 3) & 3);
      STAGE_V(gp + 1, (gp + 1) & 1);
    }

    const int ktA = (t0 + lt)*32, ktB = ktA + 32;
    const bool doA = (ktA <= q0w + 31);
    const bool doB = (ktB <= q0w + 31);
    const char* bKA = (const char*)&sK[lt & 3][0];
    const char* bKB = (const char*)&sK[(lt + 1) & 3][0];
    const char* bV  = (const char*)&sVT[gp & 1][0];

    f32x16 stA, stB;
    if (doA) stA = QK(bKA);
    if (doB) stB = QK(bKB);
    if (doA) SMPV(ktA, 0, bV, stA);
    if (doB) SMPV(ktB, 1, bV, stB);
  }

  const float l_run = l_part + __shfl_xor(l_part, 32);
  if (sl == 2) {
    const float invl = 1.0f / l_run;
    #pragma unroll
    for (int db = 0; db < 2; ++db)
      #pragma unroll
      for (int g2 = 0; g2 < 4; ++g2) {
        s16x4 o = { f2b(accO[db][g2*4+0]*invl), f2b(accO[db][g2*4+1]*invl),
                    f2b(accO[db][g2*4+2]*invl), f2b(accO[db][g2*4+3]*invl) };
        *(s16x4*)&attn[(size_t)(q0w + l5)*HID + h*HD + db*32 + g2*8 + hi*4] = o;
      }
  } else {
    // bf16 partial O + f32 partial l (validated in r11/r20: absmax unchanged)
    const int slot = (h*8 + (chunk - 8))*2 + sl;
    const int row = w*32 + l5;
    u16* po = pO + (size_t)slot*128*64 + (size_t)row*64;
    #pragma unroll
    for (int db = 0; db < 2; ++db)
      #pragma unroll
      for (int g2 = 0; g2 < 4; ++g2) {
        s16x4 o = { f2b(accO[db][g2*4+0]), f2b(accO[db][g2*4+1]),
                    f2b(accO[db][g2*4+2]), f2b(accO[db][g2*4+3]) };
        *(s16x4*)&po[db*32 + g2*8 + hi*4] = o;
      }
    if (lane < 32)
      pL[(size_t)slot*128 + row] = l_run;
  }
}

// ---------------- combine: sum the 2 K-slice partials of chunks 8..15 ---------
__global__ __launch_bounds__(256) void combine(const u16* __restrict__ pO,
                                               const float* __restrict__ pL,
                                               u16* __restrict__ attn){
  int i = blockIdx.x * 256 + threadIdx.x;
  int d8 = i & 7;
  int row = (i >> 3) & 127;
  int cc = (i >> 10) & 7;
  int h = i >> 13;
  int slot0 = (h*8 + cc)*2;
  float l = pL[(size_t)slot0*128 + row] + pL[(size_t)(slot0+1)*128 + row];
  short8 v0 = *(const short8*)&pO[((size_t)slot0*128 + row)*64 + d8*8];
  short8 v1 = *(const short8*)&pO[((size_t)(slot0+1)*128 + row)*64 + d8*8];
  const float inv = 1.0f / l;
  short8 o;
  #pragma unroll
  for (int j = 0; j < 8; ++j)
    o[j] = f2b((b2f((u16)v0[j]) + b2f((u16)v1[j])) * inv);
  const int q = (8 + cc)*128 + row;
  *(short8*)&attn[(size_t)q*HID + h*HD + d8*8] = o;
}

// ---------------- launch ----------------
extern "C" void kernel_launch(void* const* d_in, const int* in_sizes, int n_in,
                              void* d_out, int out_size, void* d_ws, size_t ws_size,
                              hipStream_t stream){
  const float* hs     = (const float*)d_in[0];
  const int*   pos    = (const int*)d_in[1];
  const float* powers = (const float*)d_in[2];
  const float* Wq     = (const float*)d_in[3];
  const float* Wk     = (const float*)d_in[4];
  const float* Wv     = (const float*)d_in[5];
  const float* Wo     = (const float*)d_in[6];
  float* out = (float*)d_out;

  char* ws = (char*)d_ws;
  auto take = [&](size_t bytes){ void* p = ws; ws += (bytes + 255) & ~(size_t)255; return p; };
  u16* hs_b  = (u16*)take((size_t)S_LEN*HID*2);
  u16* wq_b  = (u16*)take((size_t)HID*HID*2);
  u16* wk_b  = (u16*)take((size_t)NKV*HD*HID*2);
  u16* wv_b  = (u16*)take((size_t)NKV*HD*HID*2);
  u16* wo_b  = (u16*)take((size_t)HID*HID*2);
  u16* qkv   = (u16*)take((size_t)S_LEN*QKVN*2);
  u16* vt    = (u16*)take((size_t)NKV*HD*S_LEN*2);
  u16* attnb = (u16*)take((size_t)S_LEN*HID*2);
  float* cost = (float*)take((size_t)S_LEN*32*4);
  float* sint = (float*)take((size_t)S_LEN*32*4);
  u16* pO    = (u16*)take((size_t)NQH*8*2*128*64*2);     // 8.4 MB bf16 partial O
  float* pL  = (float*)take((size_t)NQH*8*2*128*4);      // 256 KB partial l

  cvt_all<<<7424, 256, 0, stream>>>(hs, Wq, Wk, Wv, Wo,
                                    hs_b, wq_b, wk_b, wv_b, wo_b,
                                    pos, powers, cost, sint);

  // fused QKV projection (+RoPE +q-scale; V written transposed into vt)
  gemm_bt<0, 4><<<dim3(QKVN/128, S_LEN/64), 256, 0, stream>>>(
      hs_b, wq_b, wk_b, wv_b, HID, HID + NKV*HD, qkv, vt,
      S_LEN, QKVN, HID, cost, sint);

  flash_attn<<<dim3(NQH, 24), 256, 0, stream>>>(qkv, vt, attnb, pO, pL);
  combine<<<1024, 256, 0, stream>>>(pO, pL, attnb);

  gemm_bt<1, 2><<<dim3(HID/64, S_LEN/64), 256, 0, stream>>>(
      attnb, wo_b, wo_b, wo_b, 1<<28, 1<<29, out, nullptr,
      S_LEN, HID, HID, nullptr, nullptr);
}

// Round 29
// 111.655 us; speedup vs baseline: 1.1733x; 1.0022x over previous
//
#include <hip/hip_runtime.h>

typedef unsigned short u16;
typedef __attribute__((ext_vector_type(8))) short short8;
typedef __attribute__((ext_vector_type(4))) short s16x4;
typedef __attribute__((ext_vector_type(4))) float f32x4;
typedef __attribute__((ext_vector_type(16))) float f32x16;
typedef __attribute__((ext_vector_type(4))) unsigned u32x4;

#define S_LEN 2048
#define HID 2048
#define NQH 32
#define NKV 8
#define HD 64
#define QKVN 3072
#define SCLOG2 0.1803368801111204f  /* 0.125 * log2(e) */

__device__ __forceinline__ short f2b(float f){
  unsigned u = __builtin_bit_cast(unsigned, f);
  u += 0x7fffu + ((u >> 16) & 1u);
  return (short)(u >> 16);
}
__device__ __forceinline__ float b2f(u16 v){
  unsigned u = ((unsigned)v) << 16;
  return __builtin_bit_cast(float, u);
}
__device__ __forceinline__ void gll16(const void* g, void* l){
  __builtin_amdgcn_global_load_lds((const __attribute__((address_space(1))) void*)g,
                                   (__attribute__((address_space(3))) void*)l, 16, 0, 0);
}
__device__ __forceinline__ unsigned cvtpk(float a, float b){
  unsigned r;
  asm("v_cvt_pk_bf16_f32 %0, %1, %2" : "=v"(r) : "v"(a), "v"(b));
  return r;
}
__device__ __forceinline__ void pswap(unsigned &a, unsigned &b){
  asm volatile("v_permlane32_swap_b32 %0, %1" : "+v"(a), "+v"(b));
}
__device__ __forceinline__ float ex2(float x){
  float r; asm("v_exp_f32 %0, %1" : "=v"(r) : "v"(x)); return r;
}

// ------- fused fp32->bf16 convert (5 tensors) + RoPE table build --------------
__global__ __launch_bounds__(256) void cvt_all(const float* __restrict__ s0,
                                               const float* __restrict__ s1,
                                               const float* __restrict__ s2,
                                               const float* __restrict__ s3,
                                               const float* __restrict__ s4,
                                               u16* __restrict__ d0, u16* __restrict__ d1,
                                               u16* __restrict__ d2, u16* __restrict__ d3,
                                               u16* __restrict__ d4,
                                               const int* __restrict__ pos,
                                               const float* __restrict__ powers,
                                               float* __restrict__ cost,
                                               float* __restrict__ sint){
  int i = blockIdx.x * 256 + threadIdx.x;
  if (i >= 1835008) {
    int j = i - 1835008;                      // S_LEN*32
    int s = j >> 5, d = j & 31;
    float p = (float)pos[s];
    float w = powers[d];
    float sig = 1.0f / (1.0f + expf(-w));
    float inv = powf(10000.0f, -sig);
    float f = p * inv;
    cost[j] = cosf(f);
    sint[j] = sinf(f);
    return;
  }
  const float* s; u16* d; int off;
  if      (i <  524288){ s = s0; d = d0; off = i; }
  else if (i < 1048576){ s = s1; d = d1; off = i -  524288; }
  else if (i < 1179648){ s = s2; d = d2; off = i - 1048576; }
  else if (i < 1310720){ s = s3; d = d3; off = i - 1179648; }
  else                 { s = s4; d = d4; off = i - 1310720; }
  const float4* s4p = (const float4*)s;
  float4 a = s4p[off*2], b = s4p[off*2+1];
  short8 o = { f2b(a.x), f2b(a.y), f2b(a.z), f2b(a.w),
               f2b(b.x), f2b(b.y), f2b(b.z), f2b(b.w) };
  *(short8*)(d + (size_t)off*8) = o;
}

// ---------------- GEMM: C[M][Ntot] = A[M][K] * B[*][K]^T  (bf16 in) -----------
// 64 x (NCOLS*32) tile. QKV: NCOLS=4 -> 768 blocks (3/CU, 48KB). Wo: NCOLS=2
// -> 1024 blocks (4/CU, 32KB). 2-phase double-buffer + both-sides XOR swizzle.
// XCD-aware bijective block swizzle (grids are multiples of 8).
// MODE 0 (QKV): bf16 out, RoPE (+attn-scale on q) cols<2560, V transposed.
// MODE 1 (Wo): f32 out.
template<int MODE, int NCOLS>
__global__ __launch_bounds__(256) void gemm_bt(const u16* __restrict__ A,
                                               const u16* __restrict__ B0,
                                               const u16* __restrict__ B1,
                                               const u16* __restrict__ B2,
                                               int n1, int n2,
                                               void* __restrict__ Cout,
                                               u16* __restrict__ vtOut,
                                               int M, int Ntot, int K,
                                               const float* __restrict__ cost,
                                               const float* __restrict__ sint){
  __shared__ alignas(16) u16 sA[2][64*64];
  __shared__ alignas(16) u16 sB[2][NCOLS*32*64];
  const int tid = threadIdx.x, lane = tid & 63, wv = tid >> 6;
  const int wr = wv >> 1, wc = wv & 1;
  // XCD-aware bijective swizzle: blocks co-resident on one XCD get a
  // contiguous tile range (shared A-panels stay in that XCD's L2).
  const int nwg = gridDim.x * gridDim.y;
  const int lin = blockIdx.y * gridDim.x + blockIdx.x;
  const int swz = (lin & 7) * (nwg >> 3) + (lin >> 3);
  const int m0 = (swz / gridDim.x) * 64;
  const int n0 = (swz % gridDim.x) * (NCOLS*32);
  const int lr = lane & 15, lg = lane >> 4;

  const u16* B;
  if (n0 < n1)      B = B0 + (size_t)n0 * K;
  else if (n0 < n2) B = B1 + (size_t)(n0 - n1) * K;
  else              B = B2 + (size_t)(n0 - n2) * K;

  const int sRow = tid >> 3;
  const int sCol = ((tid & 7) ^ (sRow & 7)) * 8;   // pre-swizzled source column
  const u16* Arow = A + (size_t)(m0 + sRow)*K + sCol;
  const u16* Brow = B + (size_t)sRow*K + sCol;

  f32x4 acc[2][NCOLS] = {};
  const int NT = K >> 6;

  #pragma unroll
  for (int i = 0; i < 2; ++i)
    gll16(Arow + (size_t)i*32*K, (char*)&sA[0][0] + i*4096 + tid*16);
  #pragma unroll
  for (int i = 0; i < NCOLS; ++i)
    gll16(Brow + (size_t)i*32*K, (char*)&sB[0][0] + i*4096 + tid*16);
  __syncthreads();

  for (int t = 0; t < NT; ++t) {
    const int cur = t & 1;
    if (t + 1 < NT) {
      const int kn = (t + 1) << 6;
      #pragma unroll
      for (int i = 0; i < 2; ++i)
        gll16(Arow + (size_t)i*32*K + kn, (char*)&sA[cur^1][0] + i*4096 + tid*16);
      #pragma unroll
      for (int i = 0; i < NCOLS; ++i)
        gll16(Brow + (size_t)i*32*K + kn, (char*)&sB[cur^1][0] + i*4096 + tid*16);
    }
    const char* bA = (const char*)&sA[cur][0];
    const char* bB = (const char*)&sB[cur][0];
    #pragma unroll
    for (int kk = 0; kk < 64; kk += 32) {
      short8 af[2], bfr[NCOLS];
      #pragma unroll
      for (int m = 0; m < 2; ++m)
        af[m] = *(const short8*)(bA + (wr*32 + m*16 + lr)*128 + ((((kk>>3) + lg) ^ (lr & 7)) << 4));
      #pragma unroll
      for (int n = 0; n < NCOLS; ++n)
        bfr[n] = *(const short8*)(bB + (wc*(NCOLS*16) + n*16 + lr)*128 + ((((kk>>3) + lg) ^ (lr & 7)) << 4));
      #pragma unroll
      for (int m = 0; m < 2; ++m)
        #pragma unroll
        for (int n = 0; n < NCOLS; ++n)
          acc[m][n] = __builtin_amdgcn_mfma_f32_16x16x32_bf16(af[m], bfr[n], acc[m][n], 0, 0, 0);
    }
    asm volatile("s_waitcnt vmcnt(0)" ::: "memory");
    __builtin_amdgcn_s_barrier();
  }

  if (MODE == 0 && n0 >= 2560) {
    #pragma unroll
    for (int n = 0; n < NCOLS; ++n) {
      const int colv = n0 - 2560 + wc*(NCOLS*16) + n*16 + lr;
      #pragma unroll
      for (int m = 0; m < 2; ++m) {
        const int row = m0 + wr*32 + m*16 + lg*4;
        s16x4 o = { f2b(acc[m][n][0]), f2b(acc[m][n][1]),
                    f2b(acc[m][n][2]), f2b(acc[m][n][3]) };
        *(s16x4*)&vtOut[(size_t)colv*S_LEN + row] = o;
      }
    }
  } else if (MODE == 0) {
    const float qsc = (n0 < n1) ? SCLOG2 : 1.0f;
    #pragma unroll
    for (int m = 0; m < 2; ++m)
      #pragma unroll
      for (int r = 0; r < 4; ++r) {
        int row = m0 + wr*32 + m*16 + lg*4 + r;
        float c0 = cost[row*32 + lr],      s0 = sint[row*32 + lr];
        float c1 = cost[row*32 + 16 + lr], s1 = sint[row*32 + 16 + lr];
        float x0 = acc[m][0][r], x1 = acc[m][1][r];
        float x2 = acc[m][2][r], x3 = acc[m][3][r];
        float o0 = (x0*c0 - x2*s0)*qsc, o2 = (x2*c0 + x0*s0)*qsc;
        float o1 = (x1*c1 - x3*s1)*qsc, o3 = (x3*c1 + x1*s1)*qsc;
        u16* cp = (u16*)Cout + (size_t)row*Ntot + n0 + wc*64 + lr;
        cp[0]  = (u16)f2b(o0);
        cp[16] = (u16)f2b(o1);
        cp[32] = (u16)f2b(o2);
        cp[48] = (u16)f2b(o3);
      }
  } else {
    #pragma unroll
    for (int m = 0; m < 2; ++m)
      #pragma unroll
      for (int n = 0; n < NCOLS; ++n)
        #pragma unroll
        for (int r = 0; r < 4; ++r) {
          int row = m0 + wr*32 + m*16 + lg*4 + r;
          int col = n0 + wc*(NCOLS*16) + n*16 + lr;
          ((float*)Cout)[(size_t)row*Ntot + col] = acc[m][n][r];
        }
  }
}

// ---------------- flash attention: 32-row K tiles + 64-col V double-tiles -----
// (round-28 structure, s_setprio REMOVED: 4-wave barrier-synced lockstep is
// the m190 regime where setprio starves staging waves). grid (32 heads, 24
// items) longest-first. chunks c<8 unsplit (finalize); c>=8 split into 2
// K-slices (bf16 partial O + f32 l -> combine). Rings: K 4x4KB; V 2x8KB
// double-tiles. LDS 32KB. Pair-ILP; 1 vmcnt(0)+barrier per pair.
__global__ __launch_bounds__(256) void flash_attn(const u16* __restrict__ qkv,
                                                  const u16* __restrict__ vt,
                                                  u16* __restrict__ attn,
                                                  u16* __restrict__ pO,
                                                  float* __restrict__ pL){
  __shared__ alignas(16) u16 sK[4][32*64];
  __shared__ alignas(16) u16 sVT[2][64*64];
  static const int c_tab[24] = {7,15,15,14,14,6,13,13,12,12,5,11,11,
                                10,10,4,9,9,8,8,3,2,1,0};
  static const int s_tab[24] = {2,0,1,0,1,2,0,1,0,1,2,0,1,
                                0,1,2,0,1,0,1,2,2,2,2};
  const int tid = threadIdx.x, lane = tid & 63, w = tid >> 6;
  const int h = blockIdx.x, kvh = h >> 2;
  const int chunk = c_tab[blockIdx.y];
  const int sl = s_tab[blockIdx.y];
  int t0, ntb;                                // in 32-row tile units (even)
  if (sl == 2) { t0 = 0; ntb = 4*chunk + 4; }
  else         { t0 = sl*2*(chunk + 1); ntb = 2*(chunk + 1); }

  const int l5 = lane & 31, hi = lane >> 5;
  const int q0w = chunk*128 + w*32;
  const int qg = q0w + l5;

  const int kRow = lane >> 3;
  const u16* srcK = qkv + (size_t)(8*w + kRow)*QKVN + HID + kvh*HD
                    + ((lane & 7) ^ (kRow & 7))*8;
  const u16* srcV = vt + (size_t)(kvh*HD + 16*w + (lane >> 3))*S_LEN
                    + ((lane & 7) ^ (lane >> 3))*8;

  auto STAGE_K = [&](int t, int buf){
    gll16(srcK + (size_t)(t*32)*QKVN, (char*)&sK[buf][0] + w*1024);
  };
  auto STAGE_V = [&](int pair, int buf){
    char* dV = (char*)&sVT[buf][0] + w*2048;
    gll16(srcV + pair*64,                    dV);
    gll16(srcV + pair*64 + (size_t)8*S_LEN,  dV + 1024);
  };

  short8 qf[4];
  #pragma unroll
  for (int cc = 0; cc < 4; ++cc)
    qf[cc] = *(const short8*)&qkv[(size_t)(q0w + l5)*QKVN + h*HD + cc*16 + hi*8];

  f32x16 accO[2] = {};
  float l_part = 0.f;

  STAGE_K(t0, 0);
  STAGE_K(t0 + 1, 1);
  STAGE_V(t0 >> 1, (t0 >> 1) & 1);

  auto QK = [&](const char* bK)->f32x16{
    short8 kf[4];
    #pragma unroll
    for (int cc = 0; cc < 4; ++cc)
      kf[cc] = *(const short8*)(bK + l5*128 + (((cc*2 + hi) ^ (l5 & 7))*16));
    f32x16 za = {}, zb = {};
    za = __builtin_amdgcn_mfma_f32_32x32x16_bf16(kf[0], qf[0], za, 0, 0, 0);
    zb = __builtin_amdgcn_mfma_f32_32x32x16_bf16(kf[1], qf[1], zb, 0, 0, 0);
    za = __builtin_amdgcn_mfma_f32_32x32x16_bf16(kf[2], qf[2], za, 0, 0, 0);
    zb = __builtin_amdgcn_mfma_f32_32x32x16_bf16(kf[3], qf[3], zb, 0, 0, 0);
    return za + zb;
  };

  auto SMPV = [&](int kt, int p, const char* bV, f32x16& z){
    if (kt + 31 > q0w) {
      #pragma unroll
      for (int r = 0; r < 16; ++r) {
        const int k = kt + (r&3) + 8*(r>>2) + 4*hi;
        float e = ex2(z[r]);
        z[r] = (k > qg) ? 0.f : e;
      }
    } else {
      #pragma unroll
      for (int r = 0; r < 16; ++r) z[r] = ex2(z[r]);
    }
    float s0 = (z[0]+z[1]) + (z[2]+z[3]);
    float s1 = (z[4]+z[5]) + (z[6]+z[7]);
    float s2 = (z[8]+z[9]) + (z[10]+z[11]);
    float s3 = (z[12]+z[13]) + (z[14]+z[15]);
    l_part += (s0+s1) + (s2+s3);

    short8 pa[2];
    {
      unsigned a0 = cvtpk(z[0],  z[1]);
      unsigned c0 = cvtpk(z[2],  z[3]);
      unsigned b0 = cvtpk(z[4],  z[5]);
      unsigned d0 = cvtpk(z[6],  z[7]);
      pswap(a0, b0); pswap(c0, d0);
      u32x4 w0 = {a0, c0, b0, d0};
      pa[0] = __builtin_bit_cast(short8, w0);
      unsigned a1 = cvtpk(z[8],  z[9]);
      unsigned c1 = cvtpk(z[10], z[11]);
      unsigned b1 = cvtpk(z[12], z[13]);
      unsigned d1 = cvtpk(z[14], z[15]);
      pswap(a1, b1); pswap(c1, d1);
      u32x4 w1 = {a1, c1, b1, d1};
      pa[1] = __builtin_bit_cast(short8, w1);
    }
    #pragma unroll
    for (int s4 = 0; s4 < 2; ++s4)
      #pragma unroll
      for (int db = 0; db < 2; ++db) {
        short8 vf = *(const short8*)(bV + (db*32 + l5)*128 + (((p*4 + s4*2 + hi) ^ (l5 & 7))*16));
        accO[db] = __builtin_amdgcn_mfma_f32_32x32x16_bf16(vf, pa[s4], accO[db], 0, 0, 0);
      }
  };

  for (int lt = 0; lt < ntb; lt += 2) {
    const int gp = (t0 + lt) >> 1;             // global V double-tile index
    asm volatile("s_waitcnt vmcnt(0)" ::: "memory");
    __builtin_amdgcn_s_barrier();
    if (lt + 2 < ntb) {
      STAGE_K(t0 + lt + 2, (lt + 2) & 3);
      STAGE_K(t0 + lt + 3, (lt + 3) & 3);
      STAGE_V(gp + 1, (gp + 1) & 1);
    }

    const int ktA = (t0 + lt)*32, ktB = ktA + 32;
    const bool doA = (ktA <= q0w + 31);
    const bool doB = (ktB <= q0w + 31);
    const char* bKA = (const char*)&sK[lt & 3][0];
    const char* bKB = (const char*)&sK[(lt + 1) & 3][0];
    const char* bV  = (const char*)&sVT[gp & 1][0];

    f32x16 stA, stB;
    if (doA) stA = QK(bKA);
    if (doB) stB = QK(bKB);
    if (doA) SMPV(ktA, 0, bV, stA);
    if (doB) SMPV(ktB, 1, bV, stB);
  }

  const float l_run = l_part + __shfl_xor(l_part, 32);
  if (sl == 2) {
    const float invl = 1.0f / l_run;
    #pragma unroll
    for (int db = 0; db < 2; ++db)
      #pragma unroll
      for (int g2 = 0; g2 < 4; ++g2) {
        s16x4 o = { f2b(accO[db][g2*4+0]*invl), f2b(accO[db][g2*4+1]*invl),
                    f2b(accO[db][g2*4+2]*invl), f2b(accO[db][g2*4+3]*invl) };
        *(s16x4*)&attn[(size_t)(q0w + l5)*HID + h*HD + db*32 + g2*8 + hi*4] = o;
      }
  } else {
    // bf16 partial O + f32 partial l (validated in r11/r20: absmax unchanged)
    const int slot = (h*8 + (chunk - 8))*2 + sl;
    const int row = w*32 + l5;
    u16* po = pO + (size_t)slot*128*64 + (size_t)row*64;
    #pragma unroll
    for (int db = 0; db < 2; ++db)
      #pragma unroll
      for (int g2 = 0; g2 < 4; ++g2) {
        s16x4 o = { f2b(accO[db][g2*4+0]), f2b(accO[db][g2*4+1]),
                    f2b(accO[db][g2*4+2]), f2b(accO[db][g2*4+3]) };
        *(s16x4*)&po[db*32 + g2*8 + hi*4] = o;
      }
    if (lane < 32)
      pL[(size_t)slot*128 + row] = l_run;
  }
}

// ---------------- combine: sum the 2 K-slice partials of chunks 8..15 ---------
__global__ __launch_bounds__(256) void combine(const u16* __restrict__ pO,
                                               const float* __restrict__ pL,
                                               u16* __restrict__ attn){
  int i = blockIdx.x * 256 + threadIdx.x;
  int d8 = i & 7;
  int row = (i >> 3) & 127;
  int cc = (i >> 10) & 7;
  int h = i >> 13;
  int slot0 = (h*8 + cc)*2;
  float l = pL[(size_t)slot0*128 + row] + pL[(size_t)(slot0+1)*128 + row];
  short8 v0 = *(const short8*)&pO[((size_t)slot0*128 + row)*64 + d8*8];
  short8 v1 = *(const short8*)&pO[((size_t)(slot0+1)*128 + row)*64 + d8*8];
  const float inv = 1.0f / l;
  short8 o;
  #pragma unroll
  for (int j = 0; j < 8; ++j)
    o[j] = f2b((b2f((u16)v0[j]) + b2f((u16)v1[j])) * inv);
  const int q = (8 + cc)*128 + row;
  *(short8*)&attn[(size_t)q*HID + h*HD + d8*8] = o;
}

// ---------------- launch ----------------
extern "C" void kernel_launch(void* const* d_in, const int* in_sizes, int n_in,
                              void* d_out, int out_size, void* d_ws, size_t ws_size,
                              hipStream_t stream){
  const float* hs     = (const float*)d_in[0];
  const int*   pos    = (const int*)d_in[1];
  const float* powers = (const float*)d_in[2];
  const float* Wq     = (const float*)d_in[3];
  const float* Wk     = (const float*)d_in[4];
  const float* Wv     = (const float*)d_in[5];
  const float* Wo     = (const float*)d_in[6];
  float* out = (float*)d_out;

  char* ws = (char*)d_ws;
  auto take = [&](size_t bytes){ void* p = ws; ws += (bytes + 255) & ~(size_t)255; return p; };
  u16* hs_b  = (u16*)take((size_t)S_LEN*HID*2);
  u16* wq_b  = (u16*)take((size_t)HID*HID*2);
  u16* wk_b  = (u16*)take((size_t)NKV*HD*HID*2);
  u16* wv_b  = (u16*)take((size_t)NKV*HD*HID*2);
  u16* wo_b  = (u16*)take((size_t)HID*HID*2);
  u16* qkv   = (u16*)take((size_t)S_LEN*QKVN*2);
  u16* vt    = (u16*)take((size_t)NKV*HD*S_LEN*2);
  u16* attnb = (u16*)take((size_t)S_LEN*HID*2);
  float* cost = (float*)take((size_t)S_LEN*32*4);
  float* sint = (float*)take((size_t)S_LEN*32*4);
  u16* pO    = (u16*)take((size_t)NQH*8*2*128*64*2);     // 8.4 MB bf16 partial O
  float* pL  = (float*)take((size_t)NQH*8*2*128*4);      // 256 KB partial l

  cvt_all<<<7424, 256, 0, stream>>>(hs, Wq, Wk, Wv, Wo,
                                    hs_b, wq_b, wk_b, wv_b, wo_b,
                                    pos, powers, cost, sint);

  // fused QKV projection (+RoPE +q-scale; V written transposed into vt)
  gemm_bt<0, 4><<<dim3(QKVN/128, S_LEN/64), 256, 0, stream>>>(
      hs_b, wq_b, wk_b, wv_b, HID, HID + NKV*HD, qkv, vt,
      S_LEN, QKVN, HID, cost, sint);

  flash_attn<<<dim3(NQH, 24), 256, 0, stream>>>(qkv, vt, attnb, pO, pL);
  combine<<<1024, 256, 0, stream>>>(pO, pL, attnb);

  gemm_bt<1, 2><<<dim3(HID/64, S_LEN/64), 256, 0, stream>>>(
      attnb, wo_b, wo_b, wo_b, 1<<28, 1<<29, out, nullptr,
      S_LEN, HID, HID, nullptr, nullptr);
}